// Round 1
// 167.997 us; speedup vs baseline: 1.1103x; 1.1103x over previous
//
#include <hip/hip_runtime.h>

namespace {

constexpr int B = 128, N = 2048, E = 32768;
constexpr int LOG2N = 11, LOG2E = 15;
constexpr int QE = E / 4;          // edges per quarter block = 8192
constexpr int LOG2QE = 13;

// ws layout (bytes)
constexpr size_t OFF_H0 = 0;                     // B*N float4 = 4 MB
constexpr size_t OFF_H1 = 4u * 1024 * 1024;      // B*N float4 = 4 MB
constexpr size_t OFF_S8 = 8u * 1024 * 1024;      // B*4 quarters * QE int2 = 32 MB
constexpr size_t OFF_RP = 40u * 1024 * 1024;     // B*4*(N+1) int ~ 4.2 MB

// One block per (batch, quarter). Builds a per-quarter CSR of (src, dt)
// records entirely in LDS, then streams it out coalesced.
// R2/R4 lesson: random fine-grained global writes/atomics cost ~60B/access
// of HBM writeback. R5 lesson: 8 random LDS atomics/edge serialize the LDS
// pipe. Here: 2 LDS atomics/edge, streaming global IO.
// R6: the 2048-wide scan now uses wave shuffles (2 barriers instead of 20).
__global__ __launch_bounds__(1024) void sort_kernel(const int* __restrict__ edge_index,
                                                    const float* __restrict__ edge_time,
                                                    const float* __restrict__ timestamp,
                                                    int2* __restrict__ sorted8,
                                                    int* __restrict__ row_ptr) {
  __shared__ int  cnt[N];        // 8 KB: counts -> cursors
  __shared__ int  wsum[16];
  __shared__ int2 rec[QE];       // 64 KB: local CSR records
  int blk = blockIdx.x, b = blk >> 2, q = blk & 3, t = threadIdx.x;

  cnt[t] = 0; cnt[t + 1024] = 0;
  __syncthreads();

  const int* src_arr = edge_index + (((size_t)(2 * b)) << LOG2E) + q * QE;
  const int* dst_arr = edge_index + (((size_t)(2 * b + 1)) << LOG2E) + q * QE;
  const float* et    = edge_time + (((size_t)b) << LOG2E) + q * QE;
  float ts = timestamp[b];

  // hist
  for (int e = t; e < QE; e += 1024) atomicAdd(&cnt[dst_arr[e]], 1);
  __syncthreads();

  // exclusive scan of 2048 counts (2 per thread): wave shuffle scan +
  // single 16-partial scan. 2 barriers total.
  int i0 = 2 * t, i1 = 2 * t + 1;
  int l0 = cnt[i0], l1 = cnt[i1];
  int sum = l0 + l1;
  int lane = t & 63, wid = t >> 6;
  int incl = sum;
#pragma unroll
  for (int d = 1; d < 64; d <<= 1) {
    int v = __shfl_up(incl, d, 64);
    if (lane >= d) incl += v;
  }
  if (lane == 63) wsum[wid] = incl;
  __syncthreads();
  if (t < 16) {
    int v = wsum[t];
    int inc = v;
#pragma unroll
    for (int d = 1; d < 16; d <<= 1) {
      int u = __shfl_up(inc, d, 16);
      if (t >= d) inc += u;
    }
    wsum[t] = inc - v;  // exclusive wave offset
  }
  __syncthreads();
  int run = wsum[wid] + (incl - sum);
  int run2 = run + l0;
  int* rp = row_ptr + (size_t)blk * (N + 1);
  rp[i0] = run;
  rp[i1] = run2;
  if (t == 1023) rp[N] = QE;
  cnt[i0] = run;   // becomes cursor
  cnt[i1] = run2;
  __syncthreads();

  // scatter into LDS CSR
  for (int e = t; e < QE; e += 1024) {
    int dst = dst_arr[e];
    int src = src_arr[e];
    float dt = ts - et[e];
    int pos = atomicAdd(&cnt[dst], 1);
    rec[pos] = make_int2(src, __float_as_int(dt));
  }
  __syncthreads();

  // coalesced stream-out (int4 = 2 records)
  const int4* rec4 = (const int4*)rec;
  int4* out4 = (int4*)(sorted8 + (((size_t)blk) << LOG2QE));
#pragma unroll
  for (int i = t; i < QE / 2; i += 1024) out4[i] = rec4[i];
}

// 2 blocks per batch, one thread per node; h staged in LDS.
// R6 changes vs previous version:
//  - q folded into Wk columns per-thread: logit = hs·wH + phi·wA (16 FMA
//    instead of 32-FMA k-projection + dot). Same fp32 quantities reassociated.
//  - single-exp online softmax: exp(-|l-m|) serves as either p (l<=m) or
//    rescale (l>m); bitwise identical to the 2-exp form.
//  - 4 quarter loops merged into one flattened cursor loop (wave iterates
//    max(total)≈27 instead of sum of per-quarter maxes≈38). All cursor
//    state in scalars (rule #20: no runtime-indexed arrays).
//  - 1-deep record prefetch: next sorted8 load issues before the ~90-inst
//    body, hiding L2/L3 latency. The one-past-end prefetch lands in the
//    row_ptr region (same ws allocation) and is never consumed.
__global__ __launch_bounds__(1024) void layer_kernel(const float4* __restrict__ h_in,
                                                     float4* __restrict__ h_out,
                                                     const int* __restrict__ row_ptr,
                                                     const int2* __restrict__ sorted8,
                                                     const float* __restrict__ tw,
                                                     const float* __restrict__ tb,
                                                     const float* __restrict__ Wq,
                                                     const float* __restrict__ Wk,
                                                     const float* __restrict__ Wv,
                                                     const float* __restrict__ Wo,
                                                     const float* __restrict__ bo) {
  __shared__ float4 lh[N];  // 32 KB
  int blk = blockIdx.x, b = blk >> 1, half = blk & 1, t = threadIdx.x;

  const float4* hb = h_in + (((size_t)b) << LOG2N);
  lh[t] = hb[t];
  lh[t + 1024] = hb[t + 1024];

  // uniform-address loads -> scalar loads / SGPRs
  float twf[4], tbf[4], wq[16], wkh[16], wkp[16], wvh[16], wvp[16];
#pragma unroll
  for (int j = 0; j < 4; j++) { twf[j] = tw[j]; tbf[j] = tb[j]; }
#pragma unroll
  for (int j = 0; j < 16; j++) wq[j] = Wq[j];
#pragma unroll
  for (int j = 0; j < 16; j++) { wkh[j] = Wk[j]; wkp[j] = Wk[16 + j]; }
#pragma unroll
  for (int j = 0; j < 16; j++) { wvh[j] = Wv[j]; wvp[j] = Wv[16 + j]; }
  __syncthreads();

  int n = half * 1024 + t;
  float4 hn = lh[n];
  const float RS2 = 0.70710678118654752f;
  float q0 = (hn.x * wq[0] + hn.y * wq[4] + hn.z * wq[8]  + hn.w * wq[12]) * RS2;
  float q1 = (hn.x * wq[1] + hn.y * wq[5] + hn.z * wq[9]  + hn.w * wq[13]) * RS2;
  float q2 = (hn.x * wq[2] + hn.y * wq[6] + hn.z * wq[10] + hn.w * wq[14]) * RS2;
  float q3 = (hn.x * wq[3] + hn.y * wq[7] + hn.z * wq[11] + hn.w * wq[15]) * RS2;

  // fold q (and 1/sqrt(DH)) into Wk columns: per-head logit weight vectors
  float wH0[4], wH1[4], wA[4], wB[4];
#pragma unroll
  for (int i = 0; i < 4; i++) {
    wH0[i] = q0 * wkh[i * 4 + 0] + q1 * wkh[i * 4 + 1];  // head0, h part
    wH1[i] = q2 * wkh[i * 4 + 2] + q3 * wkh[i * 4 + 3];  // head1, h part
    wA[i]  = q0 * wkp[i * 4 + 0] + q1 * wkp[i * 4 + 1];  // head0, phi part
    wB[i]  = q2 * wkp[i * 4 + 2] + q3 * wkp[i * 4 + 3];  // head1, phi part
  }

  // flattened cursor over the 4 quarter CSR segments (absolute indices)
  int stage = 0;
  int addr, rem, total;
  int b1, b2, b3, c1, c2, c3;
  {
    const int* rp0 = row_ptr + (size_t)(b * 4 + 0) * (N + 1);
    const int* rp1 = row_ptr + (size_t)(b * 4 + 1) * (N + 1);
    const int* rp2 = row_ptr + (size_t)(b * 4 + 2) * (N + 1);
    const int* rp3 = row_ptr + (size_t)(b * 4 + 3) * (N + 1);
    int s0 = rp0[n], e0 = rp0[n + 1];
    int s1 = rp1[n], e1 = rp1[n + 1];
    int s2 = rp2[n], e2 = rp2[n + 1];
    int s3 = rp3[n], e3 = rp3[n + 1];
    int c0 = e0 - s0; c1 = e1 - s1; c2 = e2 - s2; c3 = e3 - s3;
    total = c0 + c1 + c2 + c3;
    addr = ((b * 4 + 0) << LOG2QE) + s0; rem = c0;
    b1 = ((b * 4 + 1) << LOG2QE) + s1;
    b2 = ((b * 4 + 2) << LOG2QE) + s2;
    b3 = ((b * 4 + 3) << LOG2QE) + s3;
  }
  while (rem == 0 && stage < 3) {
    ++stage;
    addr = (stage == 1) ? b1 : (stage == 2) ? b2 : b3;
    rem  = (stage == 1) ? c1 : (stage == 2) ? c2 : c3;
  }

  float m0 = -INFINITY, m1 = -INFINITY;
  float s0v = 0.f, s1v = 0.f, a00 = 0.f, a01 = 0.f, a10 = 0.f, a11 = 0.f;

  int2 rcCur = sorted8[addr];  // safe even when total==0 (see header comment)
  for (int it = 0; it < total; ++it) {
    int2 rc = rcCur;
    ++addr; --rem;
    while (rem == 0 && stage < 3) {
      ++stage;
      addr = (stage == 1) ? b1 : (stage == 2) ? b2 : b3;
      rem  = (stage == 1) ? c1 : (stage == 2) ? c2 : c3;
    }
    rcCur = sorted8[addr];  // prefetch next record (junk on last iter, unused)

    float dt = __int_as_float(rc.y);
    float4 hs = lh[rc.x];
    float ph0 = __cosf(dt * twf[0] + tbf[0]);
    float ph1 = __cosf(dt * twf[1] + tbf[1]);
    float ph2 = __cosf(dt * twf[2] + tbf[2]);
    float ph3 = __cosf(dt * twf[3] + tbf[3]);

    float l0 = hs.x * wH0[0] + hs.y * wH0[1] + hs.z * wH0[2] + hs.w * wH0[3]
             + ph0 * wA[0] + ph1 * wA[1] + ph2 * wA[2] + ph3 * wA[3];
    float l1 = hs.x * wH1[0] + hs.y * wH1[1] + hs.z * wH1[2] + hs.w * wH1[3]
             + ph0 * wB[0] + ph1 * wB[1] + ph2 * wB[2] + ph3 * wB[3];

    float v0 = hs.x * wvh[0] + hs.y * wvh[4] + hs.z * wvh[8]  + hs.w * wvh[12]
             + ph0 * wvp[0] + ph1 * wvp[4] + ph2 * wvp[8]  + ph3 * wvp[12];
    float v1 = hs.x * wvh[1] + hs.y * wvh[5] + hs.z * wvh[9]  + hs.w * wvh[13]
             + ph0 * wvp[1] + ph1 * wvp[5] + ph2 * wvp[9]  + ph3 * wvp[13];
    float v2 = hs.x * wvh[2] + hs.y * wvh[6] + hs.z * wvh[10] + hs.w * wvh[14]
             + ph0 * wvp[2] + ph1 * wvp[6] + ph2 * wvp[10] + ph3 * wvp[14];
    float v3 = hs.x * wvh[3] + hs.y * wvh[7] + hs.z * wvh[11] + hs.w * wvh[15]
             + ph0 * wvp[3] + ph1 * wvp[7] + ph2 * wvp[11] + ph3 * wvp[15];

    // single-exp online softmax, head0 (c=0,1)
    float d0 = l0 - m0;
    float e0 = __expf(fminf(d0, -d0));   // exp(-|d|)
    bool  g0 = d0 > 0.f;
    float p0  = g0 ? 1.f : e0;
    float sc0 = g0 ? e0 : 1.f;
    m0 = fmaxf(m0, l0);
    s0v = s0v * sc0 + p0;
    a00 = a00 * sc0 + p0 * v0;
    a01 = a01 * sc0 + p0 * v1;
    // head1 (c=2,3)
    float d1 = l1 - m1;
    float e1 = __expf(fminf(d1, -d1));
    bool  g1 = d1 > 0.f;
    float p1  = g1 ? 1.f : e1;
    float sc1 = g1 ? e1 : 1.f;
    m1 = fmaxf(m1, l1);
    s1v = s1v * sc1 + p1;
    a10 = a10 * sc1 + p1 * v2;
    a11 = a11 * sc1 + p1 * v3;
  }

  float den0 = (s0v == 0.f) ? 1.f : s0v;
  float den1 = (s1v == 0.f) ? 1.f : s1v;
  float at0 = a00 / den0, at1 = a01 / den0, at2 = a10 / den1, at3 = a11 / den1;

  float wof[16], bof[4];
#pragma unroll
  for (int j = 0; j < 16; j++) wof[j] = Wo[j];
#pragma unroll
  for (int j = 0; j < 4; j++) bof[j] = bo[j];

  float o0 = bof[0] + at0 * wof[0] + at1 * wof[4] + at2 * wof[8]  + at3 * wof[12];
  float o1 = bof[1] + at0 * wof[1] + at1 * wof[5] + at2 * wof[9]  + at3 * wof[13];
  float o2 = bof[2] + at0 * wof[2] + at1 * wof[6] + at2 * wof[10] + at3 * wof[14];
  float o3 = bof[3] + at0 * wof[3] + at1 * wof[7] + at2 * wof[11] + at3 * wof[15];
  h_out[(((size_t)b) << LOG2N) + n] =
      make_float4(fmaxf(hn.x + o0, 0.f), fmaxf(hn.y + o1, 0.f),
                  fmaxf(hn.z + o2, 0.f), fmaxf(hn.w + o3, 0.f));
}

__global__ void final_kernel(const float4* __restrict__ h,
                             const int* __restrict__ src_index, const int* __restrict__ dst_index,
                             const float* __restrict__ timestamp,
                             const float* __restrict__ tw,
                             const float* __restrict__ tb,
                             const float* __restrict__ W_lin,
                             const float* __restrict__ b_lin,
                             float* __restrict__ out) {
  int b = threadIdx.x;
  if (b >= B) return;
  float4 sx = h[(((size_t)b) << LOG2N) + src_index[b]];
  float4 dx = h[(((size_t)b) << LOG2N) + dst_index[b]];
  float ts = timestamp[b];
  float f[12];
  f[0] = sx.x; f[1] = sx.y; f[2] = sx.z; f[3] = sx.w;
  f[4] = dx.x; f[5] = dx.y; f[6] = dx.z; f[7] = dx.w;
#pragma unroll
  for (int j = 0; j < 4; j++) f[8 + j] = __cosf(ts * tw[j] + tb[j]);
#pragma unroll
  for (int c = 0; c < 2; c++) {
    float o = b_lin[c];
#pragma unroll
    for (int j = 0; j < 12; j++) o += f[j] * W_lin[j * 2 + c];
    out[b * 2 + c] = o;
  }
}

}  // namespace

extern "C" void kernel_launch(void* const* d_in, const int* in_sizes, int n_in,
                              void* d_out, int out_size, void* d_ws, size_t ws_size,
                              hipStream_t stream) {
  (void)in_sizes; (void)n_in; (void)out_size; (void)ws_size;
  const float* x         = (const float*)d_in[0];
  const int*   edge_idx  = (const int*)d_in[1];
  const float* edge_time = (const float*)d_in[2];
  const float* timestamp = (const float*)d_in[3];
  const int*   src_index = (const int*)d_in[4];
  const int*   dst_index = (const int*)d_in[5];
  const float* time_w    = (const float*)d_in[6];
  const float* time_b    = (const float*)d_in[7];
  const float* Wq        = (const float*)d_in[8];
  const float* Wk        = (const float*)d_in[9];
  const float* Wv        = (const float*)d_in[10];
  const float* Wo        = (const float*)d_in[11];
  const float* bo        = (const float*)d_in[12];
  const float* W_lin     = (const float*)d_in[13];
  const float* b_lin     = (const float*)d_in[14];

  char* ws = (char*)d_ws;
  float4* h0      = (float4*)(ws + OFF_H0);
  float4* h1      = (float4*)(ws + OFF_H1);
  int2*   sorted8 = (int2*)(ws + OFF_S8);
  int*    row_ptr = (int*)(ws + OFF_RP);

  sort_kernel<<<4 * B, 1024, 0, stream>>>(edge_idx, edge_time, timestamp, sorted8, row_ptr);

  layer_kernel<<<2 * B, 1024, 0, stream>>>((const float4*)x, h1, row_ptr, sorted8,
                                           time_w, time_b,
                                           Wq + 0 * 16, Wk + 0 * 32, Wv + 0 * 32,
                                           Wo + 0 * 16, bo + 0 * 4);
  layer_kernel<<<2 * B, 1024, 0, stream>>>(h1, h0, row_ptr, sorted8,
                                           time_w, time_b,
                                           Wq + 1 * 16, Wk + 1 * 32, Wv + 1 * 32,
                                           Wo + 1 * 16, bo + 1 * 4);

  final_kernel<<<1, 128, 0, stream>>>(h0, src_index, dst_index, timestamp, time_w, time_b,
                                      W_lin, b_lin, (float*)d_out);
}